// Round 9
// baseline (163.788 us; speedup 1.0000x reference)
//
#include <hip/hip_runtime.h>

#define TPB 256

// Fused CIoU, 1 thread/element, r5 codegen style (the only shape that has
// allocated cleanly: serial chains, named scalars, shuffles ONLY in the
// final reduction; r3/r4 arrays, r6/r8 in-loop shuffles, r7 global hoists
// all spilled to scratch).
//
// Intersection area via Green's theorem on clipped edges:
//   2*area(A∩B) = sum over directed edges of cross(P(t0),P(t1))
//               = sum (t1-t0)*cross(P,D),  [t0,t1] clipped to other's planes.
// Hull area via Jarvis march with candidate initialized to the negated
// incoming direction (removes the valid/d2 checks; self-point gives cr=0,
// never taken).
__global__ __launch_bounds__(TPB, 3) void ciou_fused(
    const float* __restrict__ A,
    const float* __restrict__ Bq,
    float* __restrict__ out,
    double* __restrict__ acc,
    unsigned int* __restrict__ cnt,
    int nbatch, int nblocks)
{
    const int t = threadIdx.x;
    const int i0 = blockIdx.x * TPB + t;
    const bool live = (i0 < nbatch);
    const int i = live ? i0 : (nbatch - 1);

    float ax0,ax1,ax2,ax3,ax4,ax5,ax6,ax7;
    float ay0,ay1,ay2,ay3,ay4,ay5,ay6,ay7;
    float bx0,bx1,bx2,bx3,bx4,bx5,bx6,bx7;
    float by0,by1,by2,by3,by4,by5,by6,by7;
    {
        const float4* pa = (const float4*)(A + (size_t)i * 16);
        const float4* pb = (const float4*)(Bq + (size_t)i * 16);
        float4 q;
        q = pa[0]; ax0=q.x; ay0=q.y; ax1=q.z; ay1=q.w;
        q = pa[1]; ax2=q.x; ay2=q.y; ax3=q.z; ay3=q.w;
        q = pa[2]; ax4=q.x; ay4=q.y; ax5=q.z; ay5=q.w;
        q = pa[3]; ax6=q.x; ay6=q.y; ax7=q.z; ay7=q.w;
        q = pb[0]; bx0=q.x; by0=q.y; bx1=q.z; by1=q.w;
        q = pb[1]; bx2=q.x; by2=q.y; bx3=q.z; by3=q.w;
        q = pb[2]; bx4=q.x; by4=q.y; bx5=q.z; by5=q.w;
        q = pb[3]; bx6=q.x; by6=q.y; bx7=q.z; by7=q.w;
    }

    const float INFP = __builtin_inff();
    float inter2 = 0.f;
    float area_a, area_b;

    // aa = Ex*Py - Ey*Px - cQ ; bb = Ex*Dy - Ey*Dx ; keep t0/t1 serial (2 temps)
#define HP(EX,EY,CQ) { \
        float aa = fmaf((EX), Py, -fmaf((EY), Px, (CQ))); \
        float bb = (EX)*Dy - (EY)*Dx; \
        float tc = __fdividef(-aa, bb); \
        t0 = fmaxf(t0, (bb > 0.f) ? tc : -INFP); \
        t1 = fminf(t1, (bb < 0.f) ? tc :  INFP); }

#define EDGE8(PX,PY,DX,DY) { \
        const float Px = (PX), Py = (PY); \
        const float Dx = (DX), Dy = (DY); \
        float t0 = 0.f, t1 = 1.f; \
        HP(eq0x,eq0y,cq0) HP(eq1x,eq1y,cq1) HP(eq2x,eq2y,cq2) HP(eq3x,eq3y,cq3) \
        HP(eq4x,eq4y,cq4) HP(eq5x,eq5y,cq5) HP(eq6x,eq6y,cq6) HP(eq7x,eq7y,cq7) \
        float dt = t1 - t0; \
        float cpd = Px*Dy - Py*Dx; \
        inter2 += (dt > 0.f) ? dt*cpd : 0.f; }

    // ---- Pass 1: A's edges clipped by B's half-planes (scoped hoists) ----
    {
        float eq0x=bx1-bx0, eq0y=by1-by0, eq1x=bx2-bx1, eq1y=by2-by1;
        float eq2x=bx3-bx2, eq2y=by3-by2, eq3x=bx4-bx3, eq3y=by4-by3;
        float eq4x=bx5-bx4, eq4y=by5-by4, eq5x=bx6-bx5, eq5y=by6-by5;
        float eq6x=bx7-bx6, eq6y=by7-by6, eq7x=bx0-bx7, eq7y=by0-by7;
        float cq0=eq0x*by0-eq0y*bx0, cq1=eq1x*by1-eq1y*bx1;
        float cq2=eq2x*by2-eq2y*bx2, cq3=eq3x*by3-eq3y*bx3;
        float cq4=eq4x*by4-eq4y*bx4, cq5=eq5x*by5-eq5y*bx5;
        float cq6=eq6x*by6-eq6y*bx6, cq7=eq7x*by7-eq7y*bx7;
        area_b = -0.5f * (cq0+cq1+cq2+cq3+cq4+cq5+cq6+cq7);  // free shoelace
        EDGE8(ax0,ay0, ax1-ax0, ay1-ay0)  EDGE8(ax1,ay1, ax2-ax1, ay2-ay1)
        EDGE8(ax2,ay2, ax3-ax2, ay3-ay2)  EDGE8(ax3,ay3, ax4-ax3, ay4-ay3)
        EDGE8(ax4,ay4, ax5-ax4, ay5-ay4)  EDGE8(ax5,ay5, ax6-ax5, ay6-ay5)
        EDGE8(ax6,ay6, ax7-ax6, ay7-ay6)  EDGE8(ax7,ay7, ax0-ax7, ay0-ay7)
    }
    // ---- Pass 2: B's edges clipped by A's half-planes ----
    {
        float eq0x=ax1-ax0, eq0y=ay1-ay0, eq1x=ax2-ax1, eq1y=ay2-ay1;
        float eq2x=ax3-ax2, eq2y=ay3-ay2, eq3x=ax4-ax3, eq3y=ay4-ay3;
        float eq4x=ax5-ax4, eq4y=ay5-ay4, eq5x=ax6-ax5, eq5y=ay6-ay5;
        float eq6x=ax7-ax6, eq6y=ay7-ay6, eq7x=ax0-ax7, eq7y=ay0-ay7;
        float cq0=eq0x*ay0-eq0y*ax0, cq1=eq1x*ay1-eq1y*ax1;
        float cq2=eq2x*ay2-eq2y*ax2, cq3=eq3x*ay3-eq3y*ax3;
        float cq4=eq4x*ay4-eq4y*ax4, cq5=eq5x*ay5-eq5y*ax5;
        float cq6=eq6x*ay6-eq6y*ax6, cq7=eq7x*ay7-eq7y*ax7;
        area_a = -0.5f * (cq0+cq1+cq2+cq3+cq4+cq5+cq6+cq7);
        EDGE8(bx0,by0, bx1-bx0, by1-by0)  EDGE8(bx1,by1, bx2-bx1, by2-by1)
        EDGE8(bx2,by2, bx3-bx2, by3-by2)  EDGE8(bx3,by3, bx4-bx3, by4-by3)
        EDGE8(bx4,by4, bx5-bx4, by5-by4)  EDGE8(bx5,by5, bx6-bx5, by6-by5)
        EDGE8(bx6,by6, bx7-bx6, by7-by6)  EDGE8(bx7,by7, bx0-bx7, by0-by7)
    }

    float inter = fmaxf(0.5f * inter2, 0.f);
    float uni = area_a + area_b - inter;
    float iou = __fdividef(inter, uni);

    // ---- Hull start: serial min by (y,x) over all 16 ----
    float stx = ax0, sty = ay0;
#define UPD(PX,PY) { \
        bool bs = ((PY) < sty) || (((PY) == sty) && ((PX) < stx)); \
        stx = bs ? (PX) : stx; sty = bs ? (PY) : sty; }
    UPD(ax1,ay1) UPD(ax2,ay2) UPD(ax3,ay3) UPD(ax4,ay4)
    UPD(ax5,ay5) UPD(ax6,ay6) UPD(ax7,ay7)
    UPD(bx0,by0) UPD(bx1,by1) UPD(bx2,by2) UPD(bx3,by3)
    UPD(bx4,by4) UPD(bx5,by5) UPD(bx6,by6) UPD(bx7,by7)

    // ---- Jarvis march, candidate seeded with negated incoming direction ----
    // All points lie left of the incoming hull edge, so any real candidate
    // beats -din (cross < 0); the self-point (v=0) gives cr=0, never taken.
    // nx/ny are cndmask-selected ORIGINAL coords -> exact done equality.
    float cxv = stx, cyv = sty, accH = 0.f;
    float pdx = 1.f, pdy = 0.f;          // reference's initial heading (1,0)
    bool done = false;
    for (int it = 0; it < 16; ++it) {
        float cdx = -pdx, cdy = -pdy;
        float nx = cxv, ny = cyv;
#define SCAN(PX,PY) { \
            float vx = (PX) - cxv, vy = (PY) - cyv; \
            float cr = cdx*vy - cdy*vx; \
            bool take = cr < 0.f; \
            nx = take ? (PX) : nx;  ny = take ? (PY) : ny; \
            cdx = take ? vx : cdx;  cdy = take ? vy : cdy; }
        SCAN(ax0,ay0) SCAN(ax1,ay1) SCAN(ax2,ay2) SCAN(ax3,ay3)
        SCAN(ax4,ay4) SCAN(ax5,ay5) SCAN(ax6,ay6) SCAN(ax7,ay7)
        SCAN(bx0,by0) SCAN(bx1,by1) SCAN(bx2,by2) SCAN(bx3,by3)
        SCAN(bx4,by4) SCAN(bx5,by5) SCAN(bx6,by6) SCAN(bx7,by7)
        accH += done ? 0.f : (cxv*ny - cyv*nx);
        done = done || (nx == stx && ny == sty);
        pdx = cdx; pdy = cdy;
        cxv = nx; cyv = ny;
        if (__all(done)) break;
    }
    float ch = 0.5f * accH;

    float val = iou - __fdividef(ch - uni, ch);
    float v = live ? val : 0.f;

    // ---- reduction: wave shuffle -> LDS(16B) -> global double atomic ----
    #pragma unroll
    for (int off = 32; off > 0; off >>= 1) v += __shfl_down(v, off);
    __shared__ float wsum[4];
    int lane = t & 63, wid = t >> 6;
    if (lane == 0) wsum[wid] = v;
    __syncthreads();
    if (t == 0) {
        double bsum = (double)wsum[0] + (double)wsum[1]
                    + (double)wsum[2] + (double)wsum[3];
        atomicAdd(acc, bsum);
        __threadfence();
        unsigned int old = atomicAdd(cnt, 1u);
        if (old == (unsigned int)(nblocks - 1)) {
            double total = atomicAdd(acc, 0.0);   // read after all adds visible
            out[0] = (float)(total / (double)nbatch);
        }
    }
}

extern "C" void kernel_launch(void* const* d_in, const int* in_sizes, int n_in,
                              void* d_out, int out_size, void* d_ws, size_t ws_size,
                              hipStream_t stream) {
    const float* a = (const float*)d_in[0];
    const float* b = (const float*)d_in[1];
    float* out = (float*)d_out;
    int nbatch = in_sizes[0] / 16;
    int nblocks = (nbatch + TPB - 1) / TPB;
    double* acc = (double*)d_ws;                          // [0,8): double sum
    unsigned int* cnt = (unsigned int*)((char*)d_ws + 8); // [8,12): counter
    hipMemsetAsync(d_ws, 0, 16, stream);
    ciou_fused<<<nblocks, TPB, 0, stream>>>(a, b, out, acc, cnt, nbatch, nblocks);
}

// Round 10
// 120.937 us; speedup vs baseline: 1.3543x; 1.3543x over previous
//
#include <hip/hip_runtime.h>

#define TPB 256

// Fused CIoU, 1 thread/element — r5 skeleton verbatim with three strictly
// LOCAL tweaks (no new cross-block live values):
//   1. HP: empty-flag dropped (measure-zero case).
//   2. EDGE epilogue: cross(P(t0),P(t1)) = (t1-t0)*cross(P,D).
//   3. March scan seeded with negated incoming direction (r9-validated).
// Codegen law (r3/r4/r6/r7/r8/r9): the backend clamps VGPRs (~84) and
// spills pressure peaks to scratch catastrophically. Only serial chains
// with block-local temps allocate cleanly. No arrays, no in-loop shuffles,
// no values hoisted across macro blocks.
__global__ __launch_bounds__(TPB, 3) void ciou_fused(
    const float* __restrict__ A,
    const float* __restrict__ Bq,
    float* __restrict__ out,
    double* __restrict__ acc,
    unsigned int* __restrict__ cnt,
    int nbatch, int nblocks)
{
    const int t = threadIdx.x;
    const int i0 = blockIdx.x * TPB + t;
    const bool live = (i0 < nbatch);
    const int i = live ? i0 : (nbatch - 1);

    float ax0,ax1,ax2,ax3,ax4,ax5,ax6,ax7;
    float ay0,ay1,ay2,ay3,ay4,ay5,ay6,ay7;
    float bx0,bx1,bx2,bx3,bx4,bx5,bx6,bx7;
    float by0,by1,by2,by3,by4,by5,by6,by7;
    {
        const float4* pa = (const float4*)(A + (size_t)i * 16);
        const float4* pb = (const float4*)(Bq + (size_t)i * 16);
        float4 q;
        q = pa[0]; ax0=q.x; ay0=q.y; ax1=q.z; ay1=q.w;
        q = pa[1]; ax2=q.x; ay2=q.y; ax3=q.z; ay3=q.w;
        q = pa[2]; ax4=q.x; ay4=q.y; ax5=q.z; ay5=q.w;
        q = pa[3]; ax6=q.x; ay6=q.y; ax7=q.z; ay7=q.w;
        q = pb[0]; bx0=q.x; by0=q.y; bx1=q.z; by1=q.w;
        q = pb[1]; bx2=q.x; by2=q.y; bx3=q.z; by3=q.w;
        q = pb[2]; bx4=q.x; by4=q.y; bx5=q.z; by5=q.w;
        q = pb[3]; bx6=q.x; by6=q.y; bx7=q.z; by7=q.w;
    }

    // Shoelace areas (input vertex order is CCW; sort_poly = rotation).
    float area_a = 0.5f * ((ax0*ay1-ay0*ax1) + (ax1*ay2-ay1*ax2)
                         + (ax2*ay3-ay2*ax3) + (ax3*ay4-ay3*ax4)
                         + (ax4*ay5-ay4*ax5) + (ax5*ay6-ay5*ax6)
                         + (ax6*ay7-ay6*ax7) + (ax7*ay0-ay7*ax0));
    float area_b = 0.5f * ((bx0*by1-by0*bx1) + (bx1*by2-by1*bx2)
                         + (bx2*by3-by2*bx3) + (bx3*by4-by3*bx4)
                         + (bx4*by5-by4*bx5) + (bx5*by6-by5*bx6)
                         + (bx6*by7-by6*bx7) + (bx7*by0-by7*bx0));

    // ---- Intersection: Green's theorem over clipped edges ----
    float inter2 = 0.f;

    // inside Q iff cross(E_Q, p - V_Q) >= 0; along edge: aa + t*bb >= 0
#define HP(QX0,QY0,QX1,QY1) { \
        float ex = (QX1)-(QX0), ey = (QY1)-(QY0); \
        float aa = ex*(Py-(QY0)) - ey*(Px-(QX0)); \
        float bb = ex*Dy - ey*Dx; \
        float tc = __fdividef(-aa, bb); \
        bool bp = bb > 0.f, bn = bb < 0.f; \
        t0 = (bp && tc > t0) ? tc : t0; \
        t1 = (bn && tc < t1) ? tc : t1; }

#define HPB HP(bx0,by0,bx1,by1) HP(bx1,by1,bx2,by2) HP(bx2,by2,bx3,by3) \
            HP(bx3,by3,bx4,by4) HP(bx4,by4,bx5,by5) HP(bx5,by5,bx6,by6) \
            HP(bx6,by6,bx7,by7) HP(bx7,by7,bx0,by0)
#define HPA HP(ax0,ay0,ax1,ay1) HP(ax1,ay1,ax2,ay2) HP(ax2,ay2,ax3,ay3) \
            HP(ax3,ay3,ax4,ay4) HP(ax4,ay4,ax5,ay5) HP(ax5,ay5,ax6,ay6) \
            HP(ax6,ay6,ax7,ay7) HP(ax7,ay7,ax0,ay0)

    // cross(P(t0),P(t1)) = (t1-t0)*cross(P,D) ; t0>=0, t1<=1 by construction
#define EDGE(PX,PY,QX,QY,HPS) { \
        const float Px = (PX), Py = (PY); \
        const float Dx = (QX) - Px, Dy = (QY) - Py; \
        float t0 = 0.f, t1 = 1.f; \
        HPS \
        float dt = t1 - t0; \
        float cpd = Px*Dy - Py*Dx; \
        inter2 += (dt > 0.f) ? dt*cpd : 0.f; }

    EDGE(ax0,ay0,ax1,ay1,HPB) EDGE(ax1,ay1,ax2,ay2,HPB)
    EDGE(ax2,ay2,ax3,ay3,HPB) EDGE(ax3,ay3,ax4,ay4,HPB)
    EDGE(ax4,ay4,ax5,ay5,HPB) EDGE(ax5,ay5,ax6,ay6,HPB)
    EDGE(ax6,ay6,ax7,ay7,HPB) EDGE(ax7,ay7,ax0,ay0,HPB)
    EDGE(bx0,by0,bx1,by1,HPA) EDGE(bx1,by1,bx2,by2,HPA)
    EDGE(bx2,by2,bx3,by3,HPA) EDGE(bx3,by3,bx4,by4,HPA)
    EDGE(bx4,by4,bx5,by5,HPA) EDGE(bx5,by5,bx6,by6,HPA)
    EDGE(bx6,by6,bx7,by7,HPA) EDGE(bx7,by7,bx0,by0,HPA)

    float inter = fmaxf(0.5f * inter2, 0.f);
    float uni = area_a + area_b - inter;
    float iou = __fdividef(inter, uni);

    // ---- Hull start: serial min by (y,x) over all 16 ----
    float stx = ax0, sty = ay0;
#define UPD(PX,PY) { \
        bool bs = ((PY) < sty) || (((PY) == sty) && ((PX) < stx)); \
        stx = bs ? (PX) : stx; sty = bs ? (PY) : sty; }
    UPD(ax1,ay1) UPD(ax2,ay2) UPD(ax3,ay3) UPD(ax4,ay4)
    UPD(ax5,ay5) UPD(ax6,ay6) UPD(ax7,ay7)
    UPD(bx0,by0) UPD(bx1,by1) UPD(bx2,by2) UPD(bx3,by3)
    UPD(bx4,by4) UPD(bx5,by5) UPD(bx6,by6) UPD(bx7,by7)

    // ---- Jarvis march, candidate seeded with negated incoming direction ----
    // (r9-validated numerics: every true candidate beats -din via cross<0;
    // the self-point gives cr==0, never taken; nx/ny select exact original
    // coords so the done-equality matches the reference's termination.)
    float cxv = stx, cyv = sty, accH = 0.f;
    float pdx = 1.f, pdy = 0.f;          // reference's initial heading (1,0)
    bool done = false;
    for (int it = 0; it < 16; ++it) {
        float cdx = -pdx, cdy = -pdy;
        float nx = cxv, ny = cyv;
#define SCAN(PX,PY) { \
            float vx = (PX) - cxv, vy = (PY) - cyv; \
            float cr = cdx*vy - cdy*vx; \
            bool take = cr < 0.f; \
            nx = take ? (PX) : nx;  ny = take ? (PY) : ny; \
            cdx = take ? vx : cdx;  cdy = take ? vy : cdy; }
        SCAN(ax0,ay0) SCAN(ax1,ay1) SCAN(ax2,ay2) SCAN(ax3,ay3)
        SCAN(ax4,ay4) SCAN(ax5,ay5) SCAN(ax6,ay6) SCAN(ax7,ay7)
        SCAN(bx0,by0) SCAN(bx1,by1) SCAN(bx2,by2) SCAN(bx3,by3)
        SCAN(bx4,by4) SCAN(bx5,by5) SCAN(bx6,by6) SCAN(bx7,by7)
        accH += done ? 0.f : (cxv*ny - cyv*nx);
        done = done || (nx == stx && ny == sty);
        pdx = cdx; pdy = cdy;
        cxv = nx; cyv = ny;
        if (__all(done)) break;
    }
    float ch = 0.5f * accH;

    float val = iou - __fdividef(ch - uni, ch);
    float v = live ? val : 0.f;

    // ---- reduction: wave shuffle -> LDS(16B) -> global double atomic ----
    #pragma unroll
    for (int off = 32; off > 0; off >>= 1) v += __shfl_down(v, off);
    __shared__ float wsum[4];
    int lane = t & 63, wid = t >> 6;
    if (lane == 0) wsum[wid] = v;
    __syncthreads();
    if (t == 0) {
        double bsum = (double)wsum[0] + (double)wsum[1]
                    + (double)wsum[2] + (double)wsum[3];
        atomicAdd(acc, bsum);
        __threadfence();
        unsigned int old = atomicAdd(cnt, 1u);
        if (old == (unsigned int)(nblocks - 1)) {
            double total = atomicAdd(acc, 0.0);   // read after all adds visible
            out[0] = (float)(total / (double)nbatch);
        }
    }
}

extern "C" void kernel_launch(void* const* d_in, const int* in_sizes, int n_in,
                              void* d_out, int out_size, void* d_ws, size_t ws_size,
                              hipStream_t stream) {
    const float* a = (const float*)d_in[0];
    const float* b = (const float*)d_in[1];
    float* out = (float*)d_out;
    int nbatch = in_sizes[0] / 16;
    int nblocks = (nbatch + TPB - 1) / TPB;
    double* acc = (double*)d_ws;                          // [0,8): double sum
    unsigned int* cnt = (unsigned int*)((char*)d_ws + 8); // [8,12): counter
    hipMemsetAsync(d_ws, 0, 16, stream);
    ciou_fused<<<nblocks, TPB, 0, stream>>>(a, b, out, acc, cnt, nbatch, nblocks);
}

// Round 11
// 113.942 us; speedup vs baseline: 1.4375x; 1.0614x over previous
//
#include <hip/hip_runtime.h>

#define TPB 256

// Fused CIoU, 1 thread/element — r10 baseline with two strictly LOCAL deltas:
//   1. __launch_bounds__(256,2): VGPR cap 256. r5/r10 clamped at 84 VGPR and
//      spilled ~13 dwords/thread (13.4 MB WRITE) despite headroom; grid only
//      offers 4 waves/SIMD, which <=128 VGPR sustains, so the higher cap
//      costs no occupancy.
//   2. HP uses the r9-validated fmax/fmin +-INF form (3 ops vs 4).
// Codegen law (r3/r4/r6/r7/r8/r9): serial chains + block-local temps only.
// No arrays, no in-loop shuffles, no cross-block hoists.
__global__ __launch_bounds__(TPB, 2) void ciou_fused(
    const float* __restrict__ A,
    const float* __restrict__ Bq,
    float* __restrict__ out,
    double* __restrict__ acc,
    unsigned int* __restrict__ cnt,
    int nbatch, int nblocks)
{
    const int t = threadIdx.x;
    const int i0 = blockIdx.x * TPB + t;
    const bool live = (i0 < nbatch);
    const int i = live ? i0 : (nbatch - 1);

    float ax0,ax1,ax2,ax3,ax4,ax5,ax6,ax7;
    float ay0,ay1,ay2,ay3,ay4,ay5,ay6,ay7;
    float bx0,bx1,bx2,bx3,bx4,bx5,bx6,bx7;
    float by0,by1,by2,by3,by4,by5,by6,by7;
    {
        const float4* pa = (const float4*)(A + (size_t)i * 16);
        const float4* pb = (const float4*)(Bq + (size_t)i * 16);
        float4 q;
        q = pa[0]; ax0=q.x; ay0=q.y; ax1=q.z; ay1=q.w;
        q = pa[1]; ax2=q.x; ay2=q.y; ax3=q.z; ay3=q.w;
        q = pa[2]; ax4=q.x; ay4=q.y; ax5=q.z; ay5=q.w;
        q = pa[3]; ax6=q.x; ay6=q.y; ax7=q.z; ay7=q.w;
        q = pb[0]; bx0=q.x; by0=q.y; bx1=q.z; by1=q.w;
        q = pb[1]; bx2=q.x; by2=q.y; bx3=q.z; by3=q.w;
        q = pb[2]; bx4=q.x; by4=q.y; bx5=q.z; by5=q.w;
        q = pb[3]; bx6=q.x; by6=q.y; bx7=q.z; by7=q.w;
    }

    // Shoelace areas (input vertex order is CCW; sort_poly = rotation).
    float area_a = 0.5f * ((ax0*ay1-ay0*ax1) + (ax1*ay2-ay1*ax2)
                         + (ax2*ay3-ay2*ax3) + (ax3*ay4-ay3*ax4)
                         + (ax4*ay5-ay4*ax5) + (ax5*ay6-ay5*ax6)
                         + (ax6*ay7-ay6*ax7) + (ax7*ay0-ay7*ax0));
    float area_b = 0.5f * ((bx0*by1-by0*bx1) + (bx1*by2-by1*bx2)
                         + (bx2*by3-by2*bx3) + (bx3*by4-by3*bx4)
                         + (bx4*by5-by4*bx5) + (bx5*by6-by5*bx6)
                         + (bx6*by7-by6*bx7) + (bx7*by0-by7*bx0));

    // ---- Intersection: Green's theorem over clipped edges ----
    const float INFP = __builtin_inff();
    float inter2 = 0.f;

    // inside Q iff cross(E_Q, p - V_Q) >= 0; along edge: aa + t*bb >= 0.
    // fmax/fmin ignore the NaN arm (bb==0 -> +-INF selected anyway).
#define HP(QX0,QY0,QX1,QY1) { \
        float ex = (QX1)-(QX0), ey = (QY1)-(QY0); \
        float aa = ex*(Py-(QY0)) - ey*(Px-(QX0)); \
        float bb = ex*Dy - ey*Dx; \
        float tc = __fdividef(-aa, bb); \
        t0 = fmaxf(t0, (bb > 0.f) ? tc : -INFP); \
        t1 = fminf(t1, (bb < 0.f) ? tc :  INFP); }

#define HPB HP(bx0,by0,bx1,by1) HP(bx1,by1,bx2,by2) HP(bx2,by2,bx3,by3) \
            HP(bx3,by3,bx4,by4) HP(bx4,by4,bx5,by5) HP(bx5,by5,bx6,by6) \
            HP(bx6,by6,bx7,by7) HP(bx7,by7,bx0,by0)
#define HPA HP(ax0,ay0,ax1,ay1) HP(ax1,ay1,ax2,ay2) HP(ax2,ay2,ax3,ay3) \
            HP(ax3,ay3,ax4,ay4) HP(ax4,ay4,ax5,ay5) HP(ax5,ay5,ax6,ay6) \
            HP(ax6,ay6,ax7,ay7) HP(ax7,ay7,ax0,ay0)

    // cross(P(t0),P(t1)) = (t1-t0)*cross(P,D) ; t0>=0, t1<=1 by construction
#define EDGE(PX,PY,QX,QY,HPS) { \
        const float Px = (PX), Py = (PY); \
        const float Dx = (QX) - Px, Dy = (QY) - Py; \
        float t0 = 0.f, t1 = 1.f; \
        HPS \
        float dt = t1 - t0; \
        float cpd = Px*Dy - Py*Dx; \
        inter2 += (dt > 0.f) ? dt*cpd : 0.f; }

    EDGE(ax0,ay0,ax1,ay1,HPB) EDGE(ax1,ay1,ax2,ay2,HPB)
    EDGE(ax2,ay2,ax3,ay3,HPB) EDGE(ax3,ay3,ax4,ay4,HPB)
    EDGE(ax4,ay4,ax5,ay5,HPB) EDGE(ax5,ay5,ax6,ay6,HPB)
    EDGE(ax6,ay6,ax7,ay7,HPB) EDGE(ax7,ay7,ax0,ay0,HPB)
    EDGE(bx0,by0,bx1,by1,HPA) EDGE(bx1,by1,bx2,by2,HPA)
    EDGE(bx2,by2,bx3,by3,HPA) EDGE(bx3,by3,bx4,by4,HPA)
    EDGE(bx4,by4,bx5,by5,HPA) EDGE(bx5,by5,bx6,by6,HPA)
    EDGE(bx6,by6,bx7,by7,HPA) EDGE(bx7,by7,bx0,by0,HPA)

    float inter = fmaxf(0.5f * inter2, 0.f);
    float uni = area_a + area_b - inter;
    float iou = __fdividef(inter, uni);

    // ---- Hull start: serial min by (y,x) over all 16 ----
    float stx = ax0, sty = ay0;
#define UPD(PX,PY) { \
        bool bs = ((PY) < sty) || (((PY) == sty) && ((PX) < stx)); \
        stx = bs ? (PX) : stx; sty = bs ? (PY) : sty; }
    UPD(ax1,ay1) UPD(ax2,ay2) UPD(ax3,ay3) UPD(ax4,ay4)
    UPD(ax5,ay5) UPD(ax6,ay6) UPD(ax7,ay7)
    UPD(bx0,by0) UPD(bx1,by1) UPD(bx2,by2) UPD(bx3,by3)
    UPD(bx4,by4) UPD(bx5,by5) UPD(bx6,by6) UPD(bx7,by7)

    // ---- Jarvis march, candidate seeded with negated incoming direction ----
    // (r9/r10-validated: every true candidate beats -din via cross<0; the
    // self-point gives cr==0, never taken; nx/ny select exact original
    // coords so the done-equality matches the reference's termination.)
    float cxv = stx, cyv = sty, accH = 0.f;
    float pdx = 1.f, pdy = 0.f;          // reference's initial heading (1,0)
    bool done = false;
    for (int it = 0; it < 16; ++it) {
        float cdx = -pdx, cdy = -pdy;
        float nx = cxv, ny = cyv;
#define SCAN(PX,PY) { \
            float vx = (PX) - cxv, vy = (PY) - cyv; \
            float cr = cdx*vy - cdy*vx; \
            bool take = cr < 0.f; \
            nx = take ? (PX) : nx;  ny = take ? (PY) : ny; \
            cdx = take ? vx : cdx;  cdy = take ? vy : cdy; }
        SCAN(ax0,ay0) SCAN(ax1,ay1) SCAN(ax2,ay2) SCAN(ax3,ay3)
        SCAN(ax4,ay4) SCAN(ax5,ay5) SCAN(ax6,ay6) SCAN(ax7,ay7)
        SCAN(bx0,by0) SCAN(bx1,by1) SCAN(bx2,by2) SCAN(bx3,by3)
        SCAN(bx4,by4) SCAN(bx5,by5) SCAN(bx6,by6) SCAN(bx7,by7)
        accH += done ? 0.f : (cxv*ny - cyv*nx);
        done = done || (nx == stx && ny == sty);
        pdx = cdx; pdy = cdy;
        cxv = nx; cyv = ny;
        if (__all(done)) break;
    }
    float ch = 0.5f * accH;

    float val = iou - __fdividef(ch - uni, ch);
    float v = live ? val : 0.f;

    // ---- reduction: wave shuffle -> LDS(16B) -> global double atomic ----
    #pragma unroll
    for (int off = 32; off > 0; off >>= 1) v += __shfl_down(v, off);
    __shared__ float wsum[4];
    int lane = t & 63, wid = t >> 6;
    if (lane == 0) wsum[wid] = v;
    __syncthreads();
    if (t == 0) {
        double bsum = (double)wsum[0] + (double)wsum[1]
                    + (double)wsum[2] + (double)wsum[3];
        atomicAdd(acc, bsum);
        __threadfence();
        unsigned int old = atomicAdd(cnt, 1u);
        if (old == (unsigned int)(nblocks - 1)) {
            double total = atomicAdd(acc, 0.0);   // read after all adds visible
            out[0] = (float)(total / (double)nbatch);
        }
    }
}

extern "C" void kernel_launch(void* const* d_in, const int* in_sizes, int n_in,
                              void* d_out, int out_size, void* d_ws, size_t ws_size,
                              hipStream_t stream) {
    const float* a = (const float*)d_in[0];
    const float* b = (const float*)d_in[1];
    float* out = (float*)d_out;
    int nbatch = in_sizes[0] / 16;
    int nblocks = (nbatch + TPB - 1) / TPB;
    double* acc = (double*)d_ws;                          // [0,8): double sum
    unsigned int* cnt = (unsigned int*)((char*)d_ws + 8); // [8,12): counter
    hipMemsetAsync(d_ws, 0, 16, stream);
    ciou_fused<<<nblocks, TPB, 0, stream>>>(a, b, out, acc, cnt, nbatch, nblocks);
}